// Round 1
// baseline (428.561 us; speedup 1.0000x reference)
//
#include <hip/hip_runtime.h>

#define S1 512
#define NIMG 64

__device__ __forceinline__ int refl(int a, int L) {
    a = (a < 0) ? (-a - 1) : a;
    a = (a >= L) ? (2 * L - 1 - a) : a;
    return a;
}

// ---------------------------------------------------------------------------
// Level 1: undecimated 5/7-tap filters, fused W-pass + H-pass + q2c.
// Tile: 64x64 output per block, 256 threads.
// ---------------------------------------------------------------------------
__global__ __launch_bounds__(256) void k_level1(
    const float* __restrict__ x,
    const float* __restrict__ h0o_g, const float* __restrict__ h1o_g,
    float* __restrict__ ll1, float* __restrict__ yh0)
{
    __shared__ float xs[70 * 71];
    __shared__ float lo_s[70 * 65];
    __shared__ float hi_s[70 * 65];

    const int t  = threadIdx.x;
    const int c0 = blockIdx.x * 64;
    const int r0 = blockIdx.y * 64;
    const int n  = blockIdx.z;
    const float* __restrict__ xn = x + (size_t)n * (S1 * S1);

    float f0[5], f1[7];
#pragma unroll
    for (int i = 0; i < 5; ++i) f0[i] = h0o_g[i];
#pragma unroll
    for (int i = 0; i < 7; ++i) f1[i] = h1o_g[i];

    // stage 1: x tile with halo 3 (70x70), symmetric reflection at edges
    for (int l = t; l < 70 * 70; l += 256) {
        int rl = l / 70, cl = l - rl * 70;
        int ar = refl(r0 - 3 + rl, S1);
        int ac = refl(c0 - 3 + cl, S1);
        xs[rl * 71 + cl] = xn[(size_t)ar * S1 + ac];
    }
    __syncthreads();

    // stage 2: row filter -> lo (5 tap), hi (7 tap); 70 rows x 64 cols
    for (int l = t; l < 70 * 64; l += 256) {
        int rl = l >> 6, cl = l & 63;
        const float* xr = &xs[rl * 71 + cl];
        float v0 = xr[0], v1 = xr[1], v2 = xr[2], v3 = xr[3],
              v4 = xr[4], v5 = xr[5], v6 = xr[6];
        float lo = f0[0]*v5 + f0[1]*v4 + f0[2]*v3 + f0[3]*v2 + f0[4]*v1;
        float hi = f1[0]*v6 + f1[1]*v5 + f1[2]*v4 + f1[3]*v3 + f1[4]*v2
                 + f1[5]*v1 + f1[6]*v0;
        lo_s[rl * 65 + cl] = lo;
        hi_s[rl * 65 + cl] = hi;
    }
    __syncthreads();

    // stage 3: column filter + q2c. 32x32 quads, 4 per thread.
    const float SQH = 0.70710678118654752440f;
    float* __restrict__ yhn = yh0 + (size_t)n * (6 * 256 * 256 * 2);
    float* __restrict__ lln = ll1 + (size_t)n * (S1 * S1);
    for (int q = t; q < 32 * 32; q += 256) {
        int qi = q >> 5, qj = q & 31;
        float llq[2][2], lhq[2][2], hlq[2][2], hhq[2][2];
#pragma unroll
        for (int cc = 0; cc < 2; ++cc) {
            const int col = 2 * qj + cc;
            float L[8];
#pragma unroll
            for (int j = 0; j < 8; ++j) L[j] = lo_s[(2 * qi + j) * 65 + col];
            llq[0][cc] = f0[0]*L[5] + f0[1]*L[4] + f0[2]*L[3] + f0[3]*L[2] + f0[4]*L[1];
            llq[1][cc] = f0[0]*L[6] + f0[1]*L[5] + f0[2]*L[4] + f0[3]*L[3] + f0[4]*L[2];
            lhq[0][cc] = f1[0]*L[6] + f1[1]*L[5] + f1[2]*L[4] + f1[3]*L[3]
                       + f1[4]*L[2] + f1[5]*L[1] + f1[6]*L[0];
            lhq[1][cc] = f1[0]*L[7] + f1[1]*L[6] + f1[2]*L[5] + f1[3]*L[4]
                       + f1[4]*L[3] + f1[5]*L[2] + f1[6]*L[1];
#pragma unroll
            for (int j = 0; j < 8; ++j) L[j] = hi_s[(2 * qi + j) * 65 + col];
            hlq[0][cc] = f0[0]*L[5] + f0[1]*L[4] + f0[2]*L[3] + f0[3]*L[2] + f0[4]*L[1];
            hlq[1][cc] = f0[0]*L[6] + f0[1]*L[5] + f0[2]*L[4] + f0[3]*L[3] + f0[4]*L[2];
            hhq[0][cc] = f1[0]*L[6] + f1[1]*L[5] + f1[2]*L[4] + f1[3]*L[3]
                       + f1[4]*L[2] + f1[5]*L[1] + f1[6]*L[0];
            hhq[1][cc] = f1[0]*L[7] + f1[1]*L[6] + f1[2]*L[5] + f1[3]*L[4]
                       + f1[4]*L[3] + f1[5]*L[2] + f1[6]*L[1];
        }
        const int oy = r0 + 2 * qi, ox = c0 + 2 * qj;
        float2 w;
        w.x = llq[0][0]; w.y = llq[0][1];
        *(float2*)&lln[(size_t)oy * S1 + ox] = w;
        w.x = llq[1][0]; w.y = llq[1][1];
        *(float2*)&lln[(size_t)(oy + 1) * S1 + ox] = w;

        const int i2 = (r0 >> 1) + qi, j2 = (c0 >> 1) + qj;
        const size_t bs = 256 * 256 * 2;
        float* __restrict__ p = yhn + ((size_t)i2 * 256 + j2) * 2;
        w.x = (lhq[0][0] - lhq[1][1]) * SQH; w.y = (lhq[0][1] + lhq[1][0]) * SQH; *(float2*)(p + 0 * bs) = w;
        w.x = (hhq[0][0] - hhq[1][1]) * SQH; w.y = (hhq[0][1] + hhq[1][0]) * SQH; *(float2*)(p + 1 * bs) = w;
        w.x = (hlq[0][0] - hlq[1][1]) * SQH; w.y = (hlq[0][1] + hlq[1][0]) * SQH; *(float2*)(p + 2 * bs) = w;
        w.x = (hlq[0][0] + hlq[1][1]) * SQH; w.y = (hlq[0][1] - hlq[1][0]) * SQH; *(float2*)(p + 3 * bs) = w;
        w.x = (hhq[0][0] + hhq[1][1]) * SQH; w.y = (hhq[0][1] - hhq[1][0]) * SQH; *(float2*)(p + 4 * bs) = w;
        w.x = (lhq[0][0] + lhq[1][1]) * SQH; w.y = (lhq[0][1] - lhq[1][0]) * SQH; *(float2*)(p + 5 * bs) = w;
    }
}

// ---------------------------------------------------------------------------
// Levels 2/3: decimating dual-tree 10-tap filters (q-shift), fused W + H + q2c.
// Output ll tile: 32x32 per block, 256 threads (1 quad per thread).
//   lowpass : Y[2i]  = sum_k h0b[k] X[refl(4i+10-2k)]
//             Y[2i+1]= sum_k h0a[k] X[refl(4i+11-2k)]
//   highpass: Y[2i]  = sum_k h1a[k] X[refl(4i+11-2k)]
//             Y[2i+1]= sum_k h1b[k] X[refl(4i+10-2k)]
// For output tile [x0, x0+32) the input window is [2*x0-8, 2*x0+71] (80 wide).
// ---------------------------------------------------------------------------
__global__ __launch_bounds__(256) void k_dfilt(
    const float* __restrict__ X, const int r,
    const float* __restrict__ h0a_g, const float* __restrict__ h0b_g,
    const float* __restrict__ h1a_g, const float* __restrict__ h1b_g,
    float* __restrict__ llo, float* __restrict__ yh)
{
    __shared__ float Xs[80 * 84];
    __shared__ float lo_s[80 * 33];
    __shared__ float hi_s[80 * 33];

    const int t  = threadIdx.x;
    const int x0 = blockIdx.x * 32;
    const int y0 = blockIdx.y * 32;
    const int n  = blockIdx.z;
    const float* __restrict__ Xn = X + (size_t)n * r * r;
    const int cb = 2 * x0 - 8, rb = 2 * y0 - 8;

    float fa0[10], fb0[10], fa1[10], fb1[10];
#pragma unroll
    for (int i = 0; i < 10; ++i) {
        fa0[i] = h0a_g[i]; fb0[i] = h0b_g[i];
        fa1[i] = h1a_g[i]; fb1[i] = h1b_g[i];
    }

    // stage 1: input tile 80x80 with reflection
    for (int l = t; l < 80 * 80; l += 256) {
        int rl = l / 80, cl = l - rl * 80;
        int ar = refl(rb + rl, r);
        int ac = refl(cb + cl, r);
        Xs[rl * 84 + cl] = Xn[(size_t)ar * r + ac];
    }
    __syncthreads();

    // stage 2: W-direction dual-tree decimating filter -> lo, hi (80 rows x 32 cols)
    {
        const int cl = t & 31;               // invariant per thread
        const bool ev = (cl & 1) == 0;
        // Per-thread dense 20-tap coefficient vectors (parity pre-selected):
        // even col: lo taps at V[18-2k] (h0b), hi taps at V[19-2k] (h1a), base 2cl
        // odd  col: lo taps at V[19-2k] (h0a), hi taps at V[18-2k] (h1b), base 2cl-2
        float cL[20], cH[20];
#pragma unroll
        for (int j = 0; j < 20; ++j) { cL[j] = 0.f; cH[j] = 0.f; }
#pragma unroll
        for (int k = 0; k < 10; ++k) {
            cL[18 - 2 * k] = ev ? fb0[k] : 0.f;
            cL[19 - 2 * k] = ev ? cL[19 - 2 * k] : fa0[k];
            cH[19 - 2 * k] = ev ? fa1[k] : cH[19 - 2 * k];
            cH[18 - 2 * k] = ev ? cH[18 - 2 * k] : fb1[k];
        }
        const int base = 2 * cl - (ev ? 0 : 2);   // always multiple of 4
        for (int rl = (t >> 5); rl < 80; rl += 8) {
            const float* Vp = &Xs[rl * 84 + base];
            float V[20];
#pragma unroll
            for (int j = 0; j < 5; ++j) {
                float4 v = *(const float4*)(Vp + 4 * j);
                V[4*j+0] = v.x; V[4*j+1] = v.y; V[4*j+2] = v.z; V[4*j+3] = v.w;
            }
            float lo = 0.f, hi = 0.f;
#pragma unroll
            for (int j = 0; j < 20; ++j) { lo += cL[j] * V[j]; hi += cH[j] * V[j]; }
            lo_s[rl * 33 + cl] = lo;
            hi_s[rl * 33 + cl] = hi;
        }
    }
    __syncthreads();

    // stage 3: H-direction filter + q2c. One 2x2 quad per thread (16x16 quads).
    {
        const int qi = t >> 4, qj = t & 15;
        float llq[2][2], lhq[2][2], hlq[2][2], hhq[2][2];
#pragma unroll
        for (int cc = 0; cc < 2; ++cc) {
            const int col = 2 * qj + cc;
            float L[20];
#pragma unroll
            for (int j = 0; j < 20; ++j) L[j] = lo_s[(4 * qi + j) * 33 + col];
            float ll_e = 0.f, ll_o = 0.f, lh_e = 0.f, lh_o = 0.f;
#pragma unroll
            for (int k = 0; k < 10; ++k) {
                float le = L[18 - 2 * k], lod = L[19 - 2 * k];
                ll_e += fb0[k] * le;
                ll_o += fa0[k] * lod;
                lh_e += fa1[k] * lod;
                lh_o += fb1[k] * le;
            }
            llq[0][cc] = ll_e; llq[1][cc] = ll_o;
            lhq[0][cc] = lh_e; lhq[1][cc] = lh_o;
#pragma unroll
            for (int j = 0; j < 20; ++j) L[j] = hi_s[(4 * qi + j) * 33 + col];
            float hl_e = 0.f, hl_o = 0.f, hh_e = 0.f, hh_o = 0.f;
#pragma unroll
            for (int k = 0; k < 10; ++k) {
                float he = L[18 - 2 * k], ho = L[19 - 2 * k];
                hl_e += fb0[k] * he;
                hl_o += fa0[k] * ho;
                hh_e += fa1[k] * ho;
                hh_o += fb1[k] * he;
            }
            hlq[0][cc] = hl_e; hlq[1][cc] = hl_o;
            hhq[0][cc] = hh_e; hhq[1][cc] = hh_o;
        }

        const int R = r >> 1, R2 = r >> 2;
        const int oy = y0 + 2 * qi, ox = x0 + 2 * qj;
        float2 w;
        w.x = llq[0][0]; w.y = llq[0][1];
        *(float2*)&llo[((size_t)n * R + oy) * R + ox] = w;
        w.x = llq[1][0]; w.y = llq[1][1];
        *(float2*)&llo[((size_t)n * R + oy + 1) * R + ox] = w;

        const float SQH = 0.70710678118654752440f;
        const int i2 = (y0 >> 1) + qi, j2 = (x0 >> 1) + qj;
        const size_t bs = (size_t)R2 * R2 * 2;
        float* __restrict__ p = yh + (size_t)n * 6 * bs + ((size_t)i2 * R2 + j2) * 2;
        w.x = (lhq[0][0] - lhq[1][1]) * SQH; w.y = (lhq[0][1] + lhq[1][0]) * SQH; *(float2*)(p + 0 * bs) = w;
        w.x = (hhq[0][0] - hhq[1][1]) * SQH; w.y = (hhq[0][1] + hhq[1][0]) * SQH; *(float2*)(p + 1 * bs) = w;
        w.x = (hlq[0][0] - hlq[1][1]) * SQH; w.y = (hlq[0][1] + hlq[1][0]) * SQH; *(float2*)(p + 2 * bs) = w;
        w.x = (hlq[0][0] + hlq[1][1]) * SQH; w.y = (hlq[0][1] - hlq[1][0]) * SQH; *(float2*)(p + 3 * bs) = w;
        w.x = (hhq[0][0] + hhq[1][1]) * SQH; w.y = (hhq[0][1] - hhq[1][0]) * SQH; *(float2*)(p + 4 * bs) = w;
        w.x = (lhq[0][0] + lhq[1][1]) * SQH; w.y = (lhq[0][1] - lhq[1][0]) * SQH; *(float2*)(p + 5 * bs) = w;
    }
}

extern "C" void kernel_launch(void* const* d_in, const int* in_sizes, int n_in,
                              void* d_out, int out_size, void* d_ws, size_t ws_size,
                              hipStream_t stream) {
    const float* x   = (const float*)d_in[0];
    const float* h0o = (const float*)d_in[1];
    const float* h1o = (const float*)d_in[2];
    const float* h0a = (const float*)d_in[3];
    const float* h0b = (const float*)d_in[4];
    const float* h1a = (const float*)d_in[5];
    const float* h1b = (const float*)d_in[6];

    float* out = (float*)d_out;
    // output layout (flat, return order): ll3, yh0, yh1, yh2
    float* ll3 = out;                       // 64*128*128          = 1,048,576
    float* yh0 = out + 1048576;             // 64*6*256*256*2      = 50,331,648
    float* yh1 = out + 51380224;            // 64*6*128*128*2      = 12,582,912
    float* yh2 = out + 63963136;            // 64*6*64*64*2        =  3,145,728

    // workspace: ll1 (64 MB) + ll2 (16 MB) = 80 MB
    float* ll1 = (float*)d_ws;              // 64*512*512 floats
    float* ll2 = ll1 + 16777216;            // 64*256*256 floats

    k_level1<<<dim3(8, 8, NIMG), 256, 0, stream>>>(x, h0o, h1o, ll1, yh0);
    k_dfilt<<<dim3(8, 8, NIMG), 256, 0, stream>>>(ll1, 512, h0a, h0b, h1a, h1b, ll2, yh1);
    k_dfilt<<<dim3(4, 4, NIMG), 256, 0, stream>>>(ll2, 256, h0a, h0b, h1a, h1b, ll3, yh2);
}

// Round 2
// 421.614 us; speedup vs baseline: 1.0165x; 1.0165x over previous
//
#include <hip/hip_runtime.h>

#define S1 512
#define NIMG 64

__device__ __forceinline__ int refl(int a, int L) {
    a = (a < 0) ? (-a - 1) : a;
    a = (a >= L) ? (2 * L - 1 - a) : a;
    return a;
}

// ---------------------------------------------------------------------------
// Level 1: undecimated 5/7-tap filters, fused W-pass + H-pass + q2c.
// 64x64 output tile per block, processed as two 32-row halves to keep LDS at
// ~31.6 KB (5 blocks/CU). All LDS access vectorized (b128).
// xs col j <-> global col c0-4+j (j in [0,72)); lo/hi row rl <-> global row
// r0+32h-3+rl (rl in [0,38)).
// ---------------------------------------------------------------------------
__global__ __launch_bounds__(256) void k_level1(
    const float* __restrict__ x,
    const float* __restrict__ h0o_g, const float* __restrict__ h1o_g,
    float* __restrict__ ll1, float* __restrict__ yh0)
{
    __shared__ float xs[38 * 72];     // 10.94 KB
    __shared__ float lo_s[38 * 68];   // 10.33 KB
    __shared__ float hi_s[38 * 68];   // 10.33 KB

    const int t  = threadIdx.x;
    const int c0 = blockIdx.x * 64;
    const int r0 = blockIdx.y * 64;
    const int n  = blockIdx.z;
    const float* __restrict__ xn  = x   + (size_t)n * (S1 * S1);
    float* __restrict__ lln       = ll1 + (size_t)n * (S1 * S1);
    float* __restrict__ yhn       = yh0 + (size_t)n * (6 * 256 * 256 * 2);

    float f0[5], f1[7];
#pragma unroll
    for (int i = 0; i < 5; ++i) f0[i] = h0o_g[i];
#pragma unroll
    for (int i = 0; i < 7; ++i) f1[i] = h1o_g[i];

    const bool colfast = (c0 >= 4) && (c0 + 67 < S1);
    const float SQH = 0.70710678118654752440f;

    for (int h = 0; h < 2; ++h) {
        const int gr0 = r0 + 32 * h - 3;

        // ---- stage 1: global -> xs (38 rows x 72 cols) ----
        if (colfast) {
            for (int l = t; l < 38 * 18; l += 256) {
                int rl = l / 18, cf = l - rl * 18;
                int ar = refl(gr0 + rl, S1);
                float4 v = *(const float4*)&xn[(size_t)ar * S1 + (c0 - 4) + 4 * cf];
                *(float4*)&xs[rl * 72 + 4 * cf] = v;
            }
        } else {
            for (int l = t; l < 38 * 72; l += 256) {
                int rl = l / 72, cl = l - rl * 72;
                xs[rl * 72 + cl] =
                    xn[(size_t)refl(gr0 + rl, S1) * S1 + refl(c0 - 4 + cl, S1)];
            }
        }
        __syncthreads();

        // ---- stage 2: row filter, 4 outputs per item ----
        // lo[c] uses xs j = c+2..c+6 ; hi[c] uses j = c+1..c+7
        for (int l = t; l < 38 * 16; l += 256) {
            int rl = l >> 4, cg = l & 15;
            const float* p = &xs[rl * 72 + 4 * cg];
            float4 va = *(const float4*)p;
            float4 vb = *(const float4*)(p + 4);
            float4 vc = *(const float4*)(p + 8);
            float V[12] = {va.x, va.y, va.z, va.w, vb.x, vb.y, vb.z, vb.w,
                           vc.x, vc.y, vc.z, vc.w};
            float lov[4], hiv[4];
#pragma unroll
            for (int cc = 0; cc < 4; ++cc) {
                lov[cc] = f0[0]*V[cc+6] + f0[1]*V[cc+5] + f0[2]*V[cc+4]
                        + f0[3]*V[cc+3] + f0[4]*V[cc+2];
                hiv[cc] = f1[0]*V[cc+7] + f1[1]*V[cc+6] + f1[2]*V[cc+5]
                        + f1[3]*V[cc+4] + f1[4]*V[cc+3] + f1[5]*V[cc+2]
                        + f1[6]*V[cc+1];
            }
            *(float4*)&lo_s[rl * 68 + 4 * cg] = make_float4(lov[0], lov[1], lov[2], lov[3]);
            *(float4*)&hi_s[rl * 68 + 4 * cg] = make_float4(hiv[0], hiv[1], hiv[2], hiv[3]);
        }
        __syncthreads();

        // ---- stage 3: column filter + q2c. thread = (row-pair qi, col4 cg) ----
        {
            const int qi = t >> 4, cg = t & 15;
            float4 Lv[8];
            float llv[2][4], lhv[2][4], hlv[2][4], hhv[2][4];

#pragma unroll
            for (int j = 0; j < 8; ++j)
                Lv[j] = *(const float4*)&lo_s[(2 * qi + j) * 68 + 4 * cg];
            {
                const float* L = (const float*)Lv;
#pragma unroll
                for (int cc = 0; cc < 4; ++cc) {
                    float Lc[8];
#pragma unroll
                    for (int j = 0; j < 8; ++j) Lc[j] = L[4 * j + cc];
                    llv[0][cc] = f0[0]*Lc[5] + f0[1]*Lc[4] + f0[2]*Lc[3] + f0[3]*Lc[2] + f0[4]*Lc[1];
                    llv[1][cc] = f0[0]*Lc[6] + f0[1]*Lc[5] + f0[2]*Lc[4] + f0[3]*Lc[3] + f0[4]*Lc[2];
                    lhv[0][cc] = f1[0]*Lc[6] + f1[1]*Lc[5] + f1[2]*Lc[4] + f1[3]*Lc[3]
                               + f1[4]*Lc[2] + f1[5]*Lc[1] + f1[6]*Lc[0];
                    lhv[1][cc] = f1[0]*Lc[7] + f1[1]*Lc[6] + f1[2]*Lc[5] + f1[3]*Lc[4]
                               + f1[4]*Lc[3] + f1[5]*Lc[2] + f1[6]*Lc[1];
                }
            }
#pragma unroll
            for (int j = 0; j < 8; ++j)
                Lv[j] = *(const float4*)&hi_s[(2 * qi + j) * 68 + 4 * cg];
            {
                const float* L = (const float*)Lv;
#pragma unroll
                for (int cc = 0; cc < 4; ++cc) {
                    float Lc[8];
#pragma unroll
                    for (int j = 0; j < 8; ++j) Lc[j] = L[4 * j + cc];
                    hlv[0][cc] = f0[0]*Lc[5] + f0[1]*Lc[4] + f0[2]*Lc[3] + f0[3]*Lc[2] + f0[4]*Lc[1];
                    hlv[1][cc] = f0[0]*Lc[6] + f0[1]*Lc[5] + f0[2]*Lc[4] + f0[3]*Lc[3] + f0[4]*Lc[2];
                    hhv[0][cc] = f1[0]*Lc[6] + f1[1]*Lc[5] + f1[2]*Lc[4] + f1[3]*Lc[3]
                               + f1[4]*Lc[2] + f1[5]*Lc[1] + f1[6]*Lc[0];
                    hhv[1][cc] = f1[0]*Lc[7] + f1[1]*Lc[6] + f1[2]*Lc[5] + f1[3]*Lc[4]
                               + f1[4]*Lc[3] + f1[5]*Lc[2] + f1[6]*Lc[1];
                }
            }

            const int oy = r0 + 32 * h + 2 * qi, ox = c0 + 4 * cg;
            *(float4*)&lln[(size_t)oy * S1 + ox] =
                make_float4(llv[0][0], llv[0][1], llv[0][2], llv[0][3]);
            *(float4*)&lln[(size_t)(oy + 1) * S1 + ox] =
                make_float4(llv[1][0], llv[1][1], llv[1][2], llv[1][3]);

            // q2c for two quads (cols [0,1] and [2,3] of this group)
            const int i2 = (r0 >> 1) + 16 * h + qi, j2 = (c0 >> 1) + 2 * cg;
            const size_t bs = 256 * 256 * 2;
            float* __restrict__ p = yhn + ((size_t)i2 * 256 + j2) * 2;
#define BAND_Z1(X0, X1) make_float4((X0[0]-X1[1])*SQH, (X0[1]+X1[0])*SQH, \
                                    (X0[2]-X1[3])*SQH, (X0[3]+X1[2])*SQH)
#define BAND_Z2(X0, X1) make_float4((X0[0]+X1[1])*SQH, (X0[1]-X1[0])*SQH, \
                                    (X0[2]+X1[3])*SQH, (X0[3]-X1[2])*SQH)
            *(float4*)(p + 0 * bs) = BAND_Z1(lhv[0], lhv[1]);
            *(float4*)(p + 1 * bs) = BAND_Z1(hhv[0], hhv[1]);
            *(float4*)(p + 2 * bs) = BAND_Z1(hlv[0], hlv[1]);
            *(float4*)(p + 3 * bs) = BAND_Z2(hlv[0], hlv[1]);
            *(float4*)(p + 4 * bs) = BAND_Z2(hhv[0], hhv[1]);
            *(float4*)(p + 5 * bs) = BAND_Z2(lhv[0], lhv[1]);
#undef BAND_Z1
#undef BAND_Z2
        }
        __syncthreads();
    }
}

// ---------------------------------------------------------------------------
// Levels 2/3: decimating dual-tree 10-tap filters, fused W + H + q2c.
// 32x32 output tile. Even/odd columns of a pair share the same 20-float
// window (base 4*cp), so one thread computes both (no zero-padded taps).
// ---------------------------------------------------------------------------
__global__ __launch_bounds__(256) void k_dfilt(
    const float* __restrict__ X, const int r,
    const float* __restrict__ h0a_g, const float* __restrict__ h0b_g,
    const float* __restrict__ h1a_g, const float* __restrict__ h1b_g,
    float* __restrict__ llo, float* __restrict__ yh)
{
    __shared__ float Xs[80 * 84];     // 26.25 KB
    __shared__ float lo_s[80 * 36];   // 11.25 KB
    __shared__ float hi_s[80 * 36];   // 11.25 KB

    const int t  = threadIdx.x;
    const int x0 = blockIdx.x * 32;
    const int y0 = blockIdx.y * 32;
    const int n  = blockIdx.z;
    const float* __restrict__ Xn = X + (size_t)n * r * r;
    const int cb = 2 * x0 - 8, rb = 2 * y0 - 8;

    float fa0[10], fb0[10], fa1[10], fb1[10];
#pragma unroll
    for (int i = 0; i < 10; ++i) {
        fa0[i] = h0a_g[i]; fb0[i] = h0b_g[i];
        fa1[i] = h1a_g[i]; fb1[i] = h1b_g[i];
    }

    const bool colfast = (cb >= 0) && (cb + 79 < r);

    // ---- stage 1: global -> Xs (80 x 80, stride 84) ----
    if (colfast) {
        for (int l = t; l < 80 * 20; l += 256) {
            int rl = l / 20, cf = l - rl * 20;
            int ar = refl(rb + rl, r);
            float4 v = *(const float4*)&Xn[(size_t)ar * r + cb + 4 * cf];
            *(float4*)&Xs[rl * 84 + 4 * cf] = v;
        }
    } else {
        for (int l = t; l < 80 * 80; l += 256) {
            int rl = l / 80, cl = l - rl * 80;
            Xs[rl * 84 + cl] = Xn[(size_t)refl(rb + rl, r) * r + refl(cb + cl, r)];
        }
    }
    __syncthreads();

    // ---- stage 2: W-direction decimating filter, one col-pair per item ----
    for (int l = t; l < 80 * 16; l += 256) {
        int rl = l >> 4, cp = l & 15;
        const float* p = &Xs[rl * 84 + 4 * cp];
        float V[20];
#pragma unroll
        for (int j = 0; j < 5; ++j) {
            float4 v = *(const float4*)(p + 4 * j);
            V[4*j+0] = v.x; V[4*j+1] = v.y; V[4*j+2] = v.z; V[4*j+3] = v.w;
        }
        float lo_e = 0.f, lo_o = 0.f, hi_e = 0.f, hi_o = 0.f;
#pragma unroll
        for (int k = 0; k < 10; ++k) {
            float ve = V[18 - 2 * k], vo = V[19 - 2 * k];
            lo_e += fb0[k] * ve;
            lo_o += fa0[k] * vo;
            hi_e += fa1[k] * vo;
            hi_o += fb1[k] * ve;
        }
        *(float2*)&lo_s[rl * 36 + 2 * cp] = make_float2(lo_e, lo_o);
        *(float2*)&hi_s[rl * 36 + 2 * cp] = make_float2(hi_e, hi_o);
    }
    __syncthreads();

    // ---- stage 3: H-direction filter + q2c, one quad per thread ----
    {
        const int qi = t >> 4, cg = t & 15;
        float2 Lv[20];
        float llq[2][2], lhq[2][2], hlq[2][2], hhq[2][2];

#pragma unroll
        for (int j = 0; j < 20; ++j)
            Lv[j] = *(const float2*)&lo_s[(4 * qi + j) * 36 + 2 * cg];
        {
            const float* L = (const float*)Lv;
#pragma unroll
            for (int cc = 0; cc < 2; ++cc) {
                float e0 = 0.f, o0 = 0.f, e1 = 0.f, o1 = 0.f;
#pragma unroll
                for (int k = 0; k < 10; ++k) {
                    float le = L[(18 - 2 * k) * 2 + cc], lo = L[(19 - 2 * k) * 2 + cc];
                    e0 += fb0[k] * le;
                    o0 += fa0[k] * lo;
                    e1 += fa1[k] * lo;
                    o1 += fb1[k] * le;
                }
                llq[0][cc] = e0; llq[1][cc] = o0;
                lhq[0][cc] = e1; lhq[1][cc] = o1;
            }
        }
#pragma unroll
        for (int j = 0; j < 20; ++j)
            Lv[j] = *(const float2*)&hi_s[(4 * qi + j) * 36 + 2 * cg];
        {
            const float* L = (const float*)Lv;
#pragma unroll
            for (int cc = 0; cc < 2; ++cc) {
                float e0 = 0.f, o0 = 0.f, e1 = 0.f, o1 = 0.f;
#pragma unroll
                for (int k = 0; k < 10; ++k) {
                    float he = L[(18 - 2 * k) * 2 + cc], ho = L[(19 - 2 * k) * 2 + cc];
                    e0 += fb0[k] * he;
                    o0 += fa0[k] * ho;
                    e1 += fa1[k] * ho;
                    o1 += fb1[k] * he;
                }
                hlq[0][cc] = e0; hlq[1][cc] = o0;
                hhq[0][cc] = e1; hhq[1][cc] = o1;
            }
        }

        const int R = r >> 1, R2 = r >> 2;
        const int oy = y0 + 2 * qi, ox = x0 + 2 * cg;
        *(float2*)&llo[((size_t)n * R + oy) * R + ox]     = make_float2(llq[0][0], llq[0][1]);
        *(float2*)&llo[((size_t)n * R + oy + 1) * R + ox] = make_float2(llq[1][0], llq[1][1]);

        const float SQH = 0.70710678118654752440f;
        const int i2 = (y0 >> 1) + qi, j2 = (x0 >> 1) + cg;
        const size_t bs = (size_t)R2 * R2 * 2;
        float* __restrict__ p = yh + (size_t)n * 6 * bs + ((size_t)i2 * R2 + j2) * 2;
        float2 w;
        w.x = (lhq[0][0] - lhq[1][1]) * SQH; w.y = (lhq[0][1] + lhq[1][0]) * SQH; *(float2*)(p + 0 * bs) = w;
        w.x = (hhq[0][0] - hhq[1][1]) * SQH; w.y = (hhq[0][1] + hhq[1][0]) * SQH; *(float2*)(p + 1 * bs) = w;
        w.x = (hlq[0][0] - hlq[1][1]) * SQH; w.y = (hlq[0][1] + hlq[1][0]) * SQH; *(float2*)(p + 2 * bs) = w;
        w.x = (hlq[0][0] + hlq[1][1]) * SQH; w.y = (hlq[0][1] - hlq[1][0]) * SQH; *(float2*)(p + 3 * bs) = w;
        w.x = (hhq[0][0] + hhq[1][1]) * SQH; w.y = (hhq[0][1] - hhq[1][0]) * SQH; *(float2*)(p + 4 * bs) = w;
        w.x = (lhq[0][0] + lhq[1][1]) * SQH; w.y = (lhq[0][1] - lhq[1][0]) * SQH; *(float2*)(p + 5 * bs) = w;
    }
}

extern "C" void kernel_launch(void* const* d_in, const int* in_sizes, int n_in,
                              void* d_out, int out_size, void* d_ws, size_t ws_size,
                              hipStream_t stream) {
    const float* x   = (const float*)d_in[0];
    const float* h0o = (const float*)d_in[1];
    const float* h1o = (const float*)d_in[2];
    const float* h0a = (const float*)d_in[3];
    const float* h0b = (const float*)d_in[4];
    const float* h1a = (const float*)d_in[5];
    const float* h1b = (const float*)d_in[6];

    float* out = (float*)d_out;
    // output layout (flat, return order): ll3, yh0, yh1, yh2
    float* ll3 = out;                       // 64*128*128          = 1,048,576
    float* yh0 = out + 1048576;             // 64*6*256*256*2      = 50,331,648
    float* yh1 = out + 51380224;            // 64*6*128*128*2      = 12,582,912
    float* yh2 = out + 63963136;            // 64*6*64*64*2        =  3,145,728

    // workspace: ll1 (64 MB) + ll2 (16 MB)
    float* ll1 = (float*)d_ws;              // 64*512*512 floats
    float* ll2 = ll1 + 16777216;            // 64*256*256 floats

    k_level1<<<dim3(8, 8, NIMG), 256, 0, stream>>>(x, h0o, h1o, ll1, yh0);
    k_dfilt<<<dim3(8, 8, NIMG), 256, 0, stream>>>(ll1, 512, h0a, h0b, h1a, h1b, ll2, yh1);
    k_dfilt<<<dim3(4, 4, NIMG), 256, 0, stream>>>(ll2, 256, h0a, h0b, h1a, h1b, ll3, yh2);
}